// Round 6
// baseline (268.261 us; speedup 1.0000x reference)
//
#include <hip/hip_runtime.h>

// Cumulative product along last dim of (4096, 32768) fp32.
// ONE WAVE PER ROW — no barriers, no LDS tables, no block phasing.
// Each wave streams its row in 64 chunks of 512 elems: lane owns 8
// contiguous floats (two adjacent dwordx4 = 2KB/wave/chunk, coalesced).
// 4-deep register ring prefetch (static indices). Per chunk: 7-mul in-lane
// scan -> 6-step shfl_up wave scan -> scalar carry -> coalesced store.
// vs R4: half the wave-scans / waitcnts / loop iters per byte, 2x bytes
// in flight per wave. nt hints restored (R5 showed plain path slower).

#define COLS   32768
#define TPB    256
#define WPB    (TPB / 64)        // 4 waves (rows) per block
#define EPL    8                 // elems per lane per chunk
#define CHUNK  (64 * EPL)        // 512 elems
#define NCHUNK (COLS / CHUNK)    // 64
#define PF     4                 // prefetch depth in chunks (8KB/wave in flight)

typedef float f32x4 __attribute__((ext_vector_type(4)));

__global__ __launch_bounds__(TPB) void cumprod_rows(const float* __restrict__ x,
                                                    float* __restrict__ out) {
    const int lane = threadIdx.x & 63;
    const int wid  = threadIdx.x >> 6;
    const int row  = blockIdx.x * WPB + wid;

    const size_t base = (size_t)row * (size_t)COLS + (size_t)lane * EPL;
    const float* px = x + base;
    float*       po = out + base;

    // ---- prime the prefetch ring (static indices only) ----
    f32x4 buf[PF][2];
    #pragma unroll
    for (int j = 0; j < PF; ++j) {
        buf[j][0] = __builtin_nontemporal_load(
            reinterpret_cast<const f32x4*>(px + j * CHUNK));
        buf[j][1] = __builtin_nontemporal_load(
            reinterpret_cast<const f32x4*>(px + j * CHUNK + 4));
    }

    float carry = 1.0f;

    for (int cc = 0; cc < NCHUNK; cc += PF) {
        #pragma unroll
        for (int j = 0; j < PF; ++j) {
            f32x4 a = buf[j][0];
            f32x4 b = buf[j][1];

            // refill this ring slot from PF chunks ahead (uniform branch)
            const int nc = cc + PF + j;
            if (nc < NCHUNK) {
                buf[j][0] = __builtin_nontemporal_load(
                    reinterpret_cast<const f32x4*>(px + nc * CHUNK));
                buf[j][1] = __builtin_nontemporal_load(
                    reinterpret_cast<const f32x4*>(px + nc * CHUNK + 4));
            }

            // in-lane inclusive scan of 8 elements
            a[1] *= a[0];
            a[2] *= a[1];
            a[3] *= a[2];
            b[0] *= a[3];
            b[1] *= b[0];
            b[2] *= b[1];
            b[3] *= b[2];

            // wave-wide inclusive scan of per-lane totals (64 lanes)
            float t = b[3];
            #pragma unroll
            for (int off = 1; off < 64; off <<= 1) {
                float u = __shfl_up(t, off);
                if (lane >= off) t *= u;
            }
            // exclusive prefix for this lane
            float ex = __shfl_up(t, 1);
            if (lane == 0) ex = 1.0f;

            const float m = carry * ex;

            // chunk total -> next carry (the only serial dependency)
            carry *= __shfl(t, 63);

            f32x4 oa, ob;
            oa[0] = a[0] * m; oa[1] = a[1] * m; oa[2] = a[2] * m; oa[3] = a[3] * m;
            ob[0] = b[0] * m; ob[1] = b[1] * m; ob[2] = b[2] * m; ob[3] = b[3] * m;
            __builtin_nontemporal_store(
                oa, reinterpret_cast<f32x4*>(po + (cc + j) * CHUNK));
            __builtin_nontemporal_store(
                ob, reinterpret_cast<f32x4*>(po + (cc + j) * CHUNK + 4));
        }
    }
}

extern "C" void kernel_launch(void* const* d_in, const int* in_sizes, int n_in,
                              void* d_out, int out_size, void* d_ws, size_t ws_size,
                              hipStream_t stream) {
    const float* x = (const float*)d_in[0];
    float* out = (float*)d_out;
    const int rows = out_size / COLS;          // 4096
    cumprod_rows<<<rows / WPB, TPB, 0, stream>>>(x, out);
}

// Round 7
// 215.732 us; speedup vs baseline: 1.2435x; 1.2435x over previous
//
#include <hip/hip_runtime.h>

// Cumulative product along last dim of (4096, 32768) fp32.
// ONE WAVE PER ROW; 128 chunks of 256 elems (64 lanes x float4, 1KB
// coalesced per vmem op); 4-deep register ring prefetch; nt loads/stores.
// vs R4 (229us): the wave-wide scan is now a pure-VALU DPP scan
// (row_shr 1/2/4/8 + row_bcast15/31 + wave_shr1 exclusive + readlane
// total) instead of 8 dependent ds_bpermute shuffles -> no LDS pipe,
// no lgkmcnt chain, ~30cyc instead of ~800cyc per chunk.

#define COLS   32768
#define TPB    256
#define WPB    (TPB / 64)        // 4 waves (rows) per block
#define CHUNK  256               // elems per chunk: 64 lanes * 4
#define NCHUNK (COLS / CHUNK)    // 128
#define PF     4                 // prefetch depth in chunks

typedef float f32x4 __attribute__((ext_vector_type(4)));

#define ONE_BITS 0x3f800000      // 1.0f as int (multiplicative identity)

// t *= dpp_shifted(t); invalid/masked-off lanes multiply by 1.0f.
template <int CTRL, int RM, int BM>
__device__ __forceinline__ float mul_dpp(float x) {
    int s = __builtin_amdgcn_update_dpp(ONE_BITS, __float_as_int(x),
                                        CTRL, RM, BM, false);
    return x * __int_as_float(s);
}

__global__ __launch_bounds__(TPB) void cumprod_rows(const float* __restrict__ x,
                                                    float* __restrict__ out) {
    const int lane = threadIdx.x & 63;
    const int wid  = threadIdx.x >> 6;
    const int row  = blockIdx.x * WPB + wid;

    const size_t base = (size_t)row * (size_t)COLS + (size_t)lane * 4;
    const float* px = x + base;
    float*       po = out + base;

    // ---- prime the prefetch ring (static indices only) ----
    f32x4 buf[PF];
    #pragma unroll
    for (int j = 0; j < PF; ++j)
        buf[j] = __builtin_nontemporal_load(
            reinterpret_cast<const f32x4*>(px + j * CHUNK));

    float carry = 1.0f;

    for (int cc = 0; cc < NCHUNK; cc += PF) {
        #pragma unroll
        for (int j = 0; j < PF; ++j) {
            f32x4 v = buf[j];

            // refill this ring slot from PF chunks ahead (uniform branch)
            const int nc = cc + PF + j;
            if (nc < NCHUNK)
                buf[j] = __builtin_nontemporal_load(
                    reinterpret_cast<const f32x4*>(px + nc * CHUNK));

            // in-lane inclusive scan of 4 elements
            v[1] *= v[0];
            v[2] *= v[1];
            v[3] *= v[2];

            // ---- wave-wide inclusive scan, pure VALU DPP ----
            float t = v[3];
            t = mul_dpp<0x111, 0xf, 0xf>(t);   // row_shr:1
            t = mul_dpp<0x112, 0xf, 0xf>(t);   // row_shr:2
            t = mul_dpp<0x114, 0xf, 0xf>(t);   // row_shr:4
            t = mul_dpp<0x118, 0xf, 0xf>(t);   // row_shr:8  (rows of 16 done)
            t = mul_dpp<0x142, 0xa, 0xf>(t);   // row_bcast:15 -> rows 1,3
            t = mul_dpp<0x143, 0xc, 0xf>(t);   // row_bcast:31 -> rows 2,3

            // exclusive prefix: lane i <- t[i-1], lane 0 <- 1.0 (wave_shr:1)
            float ex = __int_as_float(__builtin_amdgcn_update_dpp(
                ONE_BITS, __float_as_int(t), 0x138, 0xf, 0xf, false));

            const float m = carry * ex;

            // wave total (lane 63) -> next carry; uniform SGPR multiply
            carry *= __int_as_float(
                __builtin_amdgcn_readlane(__float_as_int(t), 63));

            f32x4 o;
            o[0] = v[0] * m;
            o[1] = v[1] * m;
            o[2] = v[2] * m;
            o[3] = v[3] * m;
            __builtin_nontemporal_store(
                o, reinterpret_cast<f32x4*>(po + (cc + j) * CHUNK));
        }
    }
}

extern "C" void kernel_launch(void* const* d_in, const int* in_sizes, int n_in,
                              void* d_out, int out_size, void* d_ws, size_t ws_size,
                              hipStream_t stream) {
    const float* x = (const float*)d_in[0];
    float* out = (float*)d_out;
    const int rows = out_size / COLS;          // 4096
    cumprod_rows<<<rows / WPB, TPB, 0, stream>>>(x, out);
}